// Round 15
// baseline (1467.020 us; speedup 1.0000x reference)
//
#include <hip/hip_runtime.h>

// PositionAwareAttention: S=8192, B=64, D=512, A=256, all fp32 I/O.
// R15 = R12 structure (die-after-one-tile, BM=32, 4 blocks/CU) with the TWO
// MEMORY PHASES OVERLAPPED: W is loaded into registers at block start,
// issued back-to-back with the x stage loads (disjoint fabrics: x=HBM,
// Wp=L2; vmcnt in-order retirement lets x-converts wait only on the older
// x loads). K-loop is then pure LDS+MFMA. 512 thr / 8 waves x (32 rows x
// 32 acols): wreg = 128 VGPR/wave, ~200 total <= 256 cap at 8 waves/SIMD
// -> 4 blocks/CU = 32 waves/CU (full occupancy; R12 had 16).
// R13 NT hints + R14 stagger reverted (null / negative).
// k3 combines 256 tile-partials per b. bt omitted (softmax shift-invariant).

#define S_DIM 8192
#define B_DIM 64
#define D_DIM 512
#define A_DIM 256
#define BM 32
#define NTILES 256            // S / BM

typedef _Float16 half8 __attribute__((ext_vector_type(8)));
typedef float f32x4 __attribute__((ext_vector_type(4)));

__device__ __forceinline__ float tanh_fast(float x) {
  // tanh(x) = 1 - 2/(exp(2x)+1); exp->inf/0 saturates correctly to +/-1
  float e = __expf(2.0f * x);
  return 1.0f - 2.0f * __builtin_amdgcn_rcpf(e + 1.0f);
}

// Pack Wx (A=256 x K=512 f32) -> fp16 fragment tiles (R4 layout).
// elem (a=ta*16+fr, k=tk*32+fg*8+j) at Wp[(ta*16+tk)*512 + (fg*16+fr)*8 + j]
__global__ void __launch_bounds__(256)
convw_kernel(const float* __restrict__ Wx, _Float16* __restrict__ Wp) {
  const int idx = (blockIdx.x * 256 + threadIdx.x) * 8;
  const int a = idx >> 9;
  const int k = idx & 511;
  f32x4 va = *(const f32x4*)(Wx + idx);
  f32x4 vb = *(const f32x4*)(Wx + idx + 4);
  half8 hx;
#pragma unroll
  for (int i = 0; i < 4; ++i) { hx[i] = (_Float16)va[i]; hx[4 + i] = (_Float16)vb[i]; }
  const int ta = a >> 4, fr = a & 15;
  const int tk = k >> 5, fg = (k >> 3) & 3;
  *(half8*)(Wp + (ta * 16 + tk) * 512 + (fg * 16 + fr) * 8) = hx;
}

__global__ void __launch_bounds__(256)
whb_kernel(const float* __restrict__ h, const float* __restrict__ Wh,
           const float* __restrict__ bx, float* __restrict__ whb) {
  __shared__ float hs[D_DIM];
  const int b = blockIdx.x, tid = threadIdx.x;
  hs[tid] = h[b * D_DIM + tid];
  hs[tid + 256] = h[b * D_DIM + 256 + tid];
  __syncthreads();
  const int g = tid >> 4, i = tid & 15;
  for (int pass = 0; pass < 16; ++pass) {
    const int a = pass * 16 + g;
    const f32x4* wrow = (const f32x4*)(Wh + (size_t)a * D_DIM);
    float dot = 0.f;
#pragma unroll
    for (int k = 0; k < 8; ++k) {
      f32x4 wv = wrow[i + k * 16];
      f32x4 hv = *(const f32x4*)(hs + (i + k * 16) * 4);
      dot += wv[0] * hv[0] + wv[1] * hv[1] + wv[2] * hv[2] + wv[3] * hv[3];
    }
#pragma unroll
    for (int mask = 1; mask < 16; mask <<= 1) dot += __shfl_xor(dot, mask, 64);
    if (i == 0) whb[b * A_DIM + a] = dot + bx[a];
  }
}

__global__ void __launch_bounds__(512, 8)
paa_main(const float* __restrict__ x, const _Float16* __restrict__ Wp,
         const float* __restrict__ whb, const float* __restrict__ Wt,
         float* __restrict__ m_arr, float* __restrict__ l_arr,
         float* __restrict__ acc_arr) {
  __shared__ _Float16 xs[BM * D_DIM];     // [32][512] f16, 16B-chunk XOR swizzle (32 KB)
  __shared__ float scorep[8 * BM];        // [8 acol-groups][32 rows]

  const int tid = threadIdx.x;            // 0..511
  const int lane = tid & 63;
  const int wv = tid >> 6;                // 0..7 (wave = 32 rows x 32 acols)
  const int b = blockIdx.x;
  const int tile = blockIdx.y;

  const int fr = lane & 15, fg = lane >> 4;
  const int akey = fr & 7;

  // ---- issue x stage loads (HBM) FIRST: srow = tid/16, sseg = tid%16
  const int srow = tid >> 4, sseg = tid & 15;
  const int skey = srow & 7;
  const float* rp = x + ((size_t)(tile * BM + srow) * B_DIM + b) * D_DIM;
  f32x4 sa[4], sb[4];
#pragma unroll
  for (int c = 0; c < 4; ++c) {
    sa[c] = *(const f32x4*)(rp + (c * 16 + sseg) * 8);
    sb[c] = *(const f32x4*)(rp + (c * 16 + sseg) * 8 + 4);
  }

  // ---- issue W loads (L2) immediately after: both streams in flight together.
  // Wave owns acols [wv*32, wv*32+32): ta = wv*2+nf. 32 x 16B = 128 VGPR.
  half8 wreg[2][16];
#pragma unroll
  for (int nf = 0; nf < 2; ++nf)
#pragma unroll
    for (int tk = 0; tk < 16; ++tk)
      wreg[nf][tk] = *(const half8*)(Wp + ((wv * 2 + nf) * 16 + tk) * 512 + lane * 8);

  // epilogue constants (per-lane acol scalars)
  float wt_a[2], whb_a[2];
#pragma unroll
  for (int nf = 0; nf < 2; ++nf) {
    wt_a[nf]  = Wt[wv * 32 + nf * 16 + fr];
    whb_a[nf] = whb[b * A_DIM + wv * 32 + nf * 16 + fr];
  }

  // ---- convert + write x (waits only the 8 older x loads; W stays in flight)
#pragma unroll
  for (int c = 0; c < 4; ++c) {
    half8 hx;
#pragma unroll
    for (int j = 0; j < 4; ++j) { hx[j] = (_Float16)sa[c][j]; hx[4 + j] = (_Float16)sb[c][j]; }
    const int ch = c * 16 + sseg;
    *(half8*)(xs + srow * D_DIM + ((ch ^ skey) * 8)) = hx;
  }
  __syncthreads();

  // ---- K-loop: pure LDS + register-MFMA (no memory ops)
  f32x4 acc[2][2];
#pragma unroll
  for (int mf = 0; mf < 2; ++mf)
#pragma unroll
    for (int nf = 0; nf < 2; ++nf) acc[mf][nf] = (f32x4){0.f, 0.f, 0.f, 0.f};
#pragma unroll
  for (int tk = 0; tk < 16; ++tk) {
    const int slot = ((tk * 4 + fg) ^ akey) * 8;
    half8 af0 = *(const half8*)(xs + (fr) * D_DIM + slot);
    half8 af1 = *(const half8*)(xs + (16 + fr) * D_DIM + slot);
    acc[0][0] = __builtin_amdgcn_mfma_f32_16x16x32_f16(af0, wreg[0][tk], acc[0][0], 0, 0, 0);
    acc[0][1] = __builtin_amdgcn_mfma_f32_16x16x32_f16(af0, wreg[1][tk], acc[0][1], 0, 0, 0);
    acc[1][0] = __builtin_amdgcn_mfma_f32_16x16x32_f16(af1, wreg[0][tk], acc[1][0], 0, 0, 0);
    acc[1][1] = __builtin_amdgcn_mfma_f32_16x16x32_f16(af1, wreg[1][tk], acc[1][1], 0, 0, 0);
  }

  // ---- epilogue: score partial for this wave's 32 acols (C frag: row=fg*4+r)
  {
    float part[2][4];
#pragma unroll
    for (int mf = 0; mf < 2; ++mf)
#pragma unroll
      for (int r = 0; r < 4; ++r) part[mf][r] = 0.f;
#pragma unroll
    for (int nf = 0; nf < 2; ++nf)
#pragma unroll
      for (int mf = 0; mf < 2; ++mf)
#pragma unroll
        for (int r = 0; r < 4; ++r)
          part[mf][r] += wt_a[nf] * tanh_fast(acc[mf][nf][r] + whb_a[nf]);
#pragma unroll
    for (int mask = 1; mask < 16; mask <<= 1)
#pragma unroll
      for (int mf = 0; mf < 2; ++mf)
#pragma unroll
        for (int r = 0; r < 4; ++r) part[mf][r] += __shfl_xor(part[mf][r], mask, 64);
    if (fr == 0) {
#pragma unroll
      for (int mf = 0; mf < 2; ++mf)
#pragma unroll
        for (int r = 0; r < 4; ++r)
          scorep[wv * BM + mf * 16 + fg * 4 + r] = part[mf][r];
    }
  }
  __syncthreads();

  // ---- tile-local softmax (32 rows; both 32-lane halves compute identically)
  const int rl = lane & 31;
  float sv = 0.f;
#pragma unroll
  for (int w = 0; w < 8; ++w) sv += scorep[w * BM + rl];
  float m = sv;
#pragma unroll
  for (int mask = 1; mask < 32; mask <<= 1) m = fmaxf(m, __shfl_xor(m, mask, 64));
  float p = __expf(sv - m);
  float lsum = p;
#pragma unroll
  for (int mask = 1; mask < 32; mask <<= 1) lsum += __shfl_xor(lsum, mask, 64);
  if (tid == 0) {
    m_arr[b * NTILES + tile] = m;
    l_arr[b * NTILES + tile] = lsum;
  }

  // ---- weighted sum from resident tile: wave owns 8 chunks (64 cols)
  {
    const int q = lane >> 3;                 // 8 row-groups of 4
    const int ch = wv * 8 + (lane & 7);      // chunk 0..63
    float wacc[8];
#pragma unroll
    for (int j = 0; j < 8; ++j) wacc[j] = 0.f;
#pragma unroll
    for (int k = 0; k < 4; ++k) {
      const int row = q * 4 + k;
      const float pr = __shfl(p, row, 64);
      half8 xv = *(const half8*)(xs + row * D_DIM + ((ch ^ (row & 7)) * 8));
#pragma unroll
      for (int j = 0; j < 8; ++j) wacc[j] += pr * (float)xv[j];
    }
#pragma unroll
    for (int j = 0; j < 8; ++j) wacc[j] += __shfl_xor(wacc[j], 8, 64);
#pragma unroll
    for (int j = 0; j < 8; ++j) wacc[j] += __shfl_xor(wacc[j], 16, 64);
#pragma unroll
    for (int j = 0; j < 8; ++j) wacc[j] += __shfl_xor(wacc[j], 32, 64);
    if (lane < 8) {
      float* ob = acc_arr + ((size_t)(b * NTILES + tile)) * D_DIM + ch * 8;
      *(f32x4*)(ob) = (f32x4){wacc[0], wacc[1], wacc[2], wacc[3]};
      *(f32x4*)(ob + 4) = (f32x4){wacc[4], wacc[5], wacc[6], wacc[7]};
    }
  }
}

__global__ void __launch_bounds__(512)
combine_kernel(const float* __restrict__ m_arr, const float* __restrict__ l_arr,
               const float* __restrict__ acc_arr, float* __restrict__ out) {
  __shared__ float ml[NTILES], ls[NTILES], wl[NTILES];
  const int b = blockIdx.x, tid = threadIdx.x;
  if (tid < NTILES) {
    ml[tid] = m_arr[b * NTILES + tid];
    ls[tid] = l_arr[b * NTILES + tid];
  }
  __syncthreads();
  float M = -1e30f;
  for (int i = 0; i < NTILES; ++i) M = fmaxf(M, ml[i]);
  if (tid < NTILES) wl[tid] = __expf(ml[tid] - M);
  __syncthreads();
  float L = 0.f;
  for (int i = 0; i < NTILES; ++i) L += wl[i] * ls[i];
  float sum = 0.f;
  const size_t base = (size_t)b * NTILES * D_DIM + tid;
  for (int i = 0; i < NTILES; ++i) sum += wl[i] * acc_arr[base + (size_t)i * D_DIM];
  out[b * D_DIM + tid] = sum / L;
}

extern "C" void kernel_launch(void* const* d_in, const int* in_sizes, int n_in,
                              void* d_out, int out_size, void* d_ws, size_t ws_size,
                              hipStream_t stream) {
  const float* x = (const float*)d_in[0];
  const float* h = (const float*)d_in[1];
  const float* Wx = (const float*)d_in[2];
  const float* bx = (const float*)d_in[3];
  const float* Wh = (const float*)d_in[4];
  const float* Wt = (const float*)d_in[5];
  // d_in[6] = bt: unused (softmax shift-invariant)

  char* ws = (char*)d_ws;
  _Float16* Wp = (_Float16*)ws;                               // 262144 B (packed)
  float* whb = (float*)(ws + 262144);                         // 65536 B
  float* m_arr = (float*)(ws + 262144 + 65536);               // 65536 B
  float* l_arr = (float*)(ws + 262144 + 65536 + 65536);       // 65536 B
  float* acc_arr = (float*)(ws + 262144 + 3 * 65536);         // 33.6 MB

  hipLaunchKernelGGL(convw_kernel, dim3(64), dim3(256), 0, stream, Wx, Wp);
  hipLaunchKernelGGL(whb_kernel, dim3(B_DIM), dim3(256), 0, stream, h, Wh, bx, whb);
  hipLaunchKernelGGL(paa_main, dim3(B_DIM, NTILES), dim3(512), 0, stream,
                     x, Wp, whb, Wt, m_arr, l_arr, acc_arr);
  hipLaunchKernelGGL(combine_kernel, dim3(B_DIM), dim3(512), 0, stream,
                     m_arr, l_arr, acc_arr, (float*)d_out);
}

// Round 16
// 364.274 us; speedup vs baseline: 4.0272x; 4.0272x over previous
//
#include <hip/hip_runtime.h>

// PositionAwareAttention: S=8192, B=64, D=512, A=256, all fp32 I/O.
// R16 = R12 (proven best 368 us: BM=32, 256 thr, 4 blocks/CU, die-after-one-
// tile, packed W streamed from L2) + CORRECTED one-time stagger.
// R14's bug: (linear>>8)&3 = generation index for replacement blocks -> every
// gen slept uniformly (pure delay). Fix: sleep ONLY the initial fill
// (linear < 1024, where linear>>8 IS the CU residency slot); replacements
// inherit their slot's phase (equal durations). Offset = solo-stage time
// (~2.6 us/slot) so the 4 slots' stage phases tile back-to-back: one block
// on HBM while 3 others K-loop(L2)/tail(VALU). Model: gen 21 -> ~10.5 us.
// R15's W-in-regs is VGPR-impossible at 4 blk/CU (spilled; reverted).
// k3 combines 256 tile-partials per b. bt omitted (softmax shift-invariant).

#define S_DIM 8192
#define B_DIM 64
#define D_DIM 512
#define A_DIM 256
#define BM 32
#define NTILES 256            // S / BM

typedef _Float16 half8 __attribute__((ext_vector_type(8)));
typedef float f32x4 __attribute__((ext_vector_type(4)));

__device__ __forceinline__ float tanh_fast(float x) {
  // tanh(x) = 1 - 2/(exp(2x)+1); exp->inf/0 saturates correctly to +/-1
  float e = __expf(2.0f * x);
  return 1.0f - 2.0f * __builtin_amdgcn_rcpf(e + 1.0f);
}

// Pack Wx (A=256 x K=512 f32) -> fp16 fragment tiles (R4 layout).
// elem (a=ta*16+fr, k=tk*32+fg*8+j) at Wp[(ta*16+tk)*512 + (fg*16+fr)*8 + j]
__global__ void __launch_bounds__(256)
convw_kernel(const float* __restrict__ Wx, _Float16* __restrict__ Wp) {
  const int idx = (blockIdx.x * 256 + threadIdx.x) * 8;
  const int a = idx >> 9;
  const int k = idx & 511;
  f32x4 va = *(const f32x4*)(Wx + idx);
  f32x4 vb = *(const f32x4*)(Wx + idx + 4);
  half8 hx;
#pragma unroll
  for (int i = 0; i < 4; ++i) { hx[i] = (_Float16)va[i]; hx[4 + i] = (_Float16)vb[i]; }
  const int ta = a >> 4, fr = a & 15;
  const int tk = k >> 5, fg = (k >> 3) & 3;
  *(half8*)(Wp + (ta * 16 + tk) * 512 + (fg * 16 + fr) * 8) = hx;
}

__global__ void __launch_bounds__(256)
whb_kernel(const float* __restrict__ h, const float* __restrict__ Wh,
           const float* __restrict__ bx, float* __restrict__ whb) {
  __shared__ float hs[D_DIM];
  const int b = blockIdx.x, tid = threadIdx.x;
  hs[tid] = h[b * D_DIM + tid];
  hs[tid + 256] = h[b * D_DIM + 256 + tid];
  __syncthreads();
  const int g = tid >> 4, i = tid & 15;
  for (int pass = 0; pass < 16; ++pass) {
    const int a = pass * 16 + g;
    const f32x4* wrow = (const f32x4*)(Wh + (size_t)a * D_DIM);
    float dot = 0.f;
#pragma unroll
    for (int k = 0; k < 8; ++k) {
      f32x4 wv = wrow[i + k * 16];
      f32x4 hv = *(const f32x4*)(hs + (i + k * 16) * 4);
      dot += wv[0] * hv[0] + wv[1] * hv[1] + wv[2] * hv[2] + wv[3] * hv[3];
    }
#pragma unroll
    for (int mask = 1; mask < 16; mask <<= 1) dot += __shfl_xor(dot, mask, 64);
    if (i == 0) whb[b * A_DIM + a] = dot + bx[a];
  }
}

__global__ void __launch_bounds__(256, 4)
paa_main(const float* __restrict__ x, const _Float16* __restrict__ Wp,
         const float* __restrict__ whb, const float* __restrict__ Wt,
         float* __restrict__ m_arr, float* __restrict__ l_arr,
         float* __restrict__ acc_arr) {
  __shared__ _Float16 xs[BM * D_DIM];     // [32][512] f16, 16B-chunk XOR swizzle (32 KB)
  __shared__ float scorep[4 * BM];        // [4 acol-groups][32 rows]

  const int tid = threadIdx.x;            // 0..255
  const int lane = tid & 63;
  const int wv = tid >> 6;                // 0..3 (wave = 32 rows x 64 acols)
  const int b = blockIdx.x;
  const int tile = blockIdx.y;

  // ---- one-time de-phasing: ONLY the initial fill (first 1024 dispatched
  // blocks = 4 residency passes over 256 CUs). slot = lin>>8 in 0..3; sleep
  // slot * ~2.6 us (one solo-stage time). Replacements inherit slot phase.
  {
    const int lin = tile * gridDim.x + b;   // dispatch-linear id
    if (lin < 1024) {
      const int slot = lin >> 8;
      for (int s = 0; s < slot; ++s) __builtin_amdgcn_s_sleep(97);  // ~2.6 us
    }
  }

  const int fr = lane & 15, fg = lane >> 4;
  const int akey = fr & 7;
  // wave's packed-W base: acols [wv*64, wv*64+64), lane-contiguous 1 KB frags
  const _Float16* wp = Wp + wv * (4 * 16 * 512) + lane * 8;

  // epilogue constants, hoisted (per-lane acol scalars for nf=0..3)
  float wt_a[4], whb_a[4];
#pragma unroll
  for (int nf = 0; nf < 4; ++nf) {
    wt_a[nf]  = Wt[wv * 64 + nf * 16 + fr];
    whb_a[nf] = whb[b * A_DIM + wv * 64 + nf * 16 + fr];
  }

  // ---- stage: 32 rows x 512 f32 -> swizzled fp16 LDS.
  // Thread = (srow 0..31, sseg 0..7); pair p covers f32 cols p*64+sseg*8..+7
  // -> fp16 chunk ch = p*8+sseg; p = 0..7 covers all 64 chunks.
  const int srow = tid >> 3, sseg = tid & 7;
  const int skey = srow & 7;
  {
    const float* rp = x + ((size_t)(tile * BM + srow) * B_DIM + b) * D_DIM;
    f32x4 sa[4], sb[4];
#pragma unroll
    for (int p = 0; p < 4; ++p) {
      sa[p] = *(const f32x4*)(rp + p * 64 + sseg * 8);
      sb[p] = *(const f32x4*)(rp + p * 64 + sseg * 8 + 4);
    }
#pragma unroll
    for (int p = 0; p < 4; ++p) {
      half8 hx;
#pragma unroll
      for (int j = 0; j < 4; ++j) { hx[j] = (_Float16)sa[p][j]; hx[4 + j] = (_Float16)sb[p][j]; }
      const int ch = p * 8 + sseg;
      *(half8*)(xs + srow * D_DIM + ((ch ^ skey) * 8)) = hx;
    }
#pragma unroll
    for (int p = 0; p < 4; ++p) {
      sa[p] = *(const f32x4*)(rp + (4 + p) * 64 + sseg * 8);
      sb[p] = *(const f32x4*)(rp + (4 + p) * 64 + sseg * 8 + 4);
    }
#pragma unroll
    for (int p = 0; p < 4; ++p) {
      half8 hx;
#pragma unroll
      for (int j = 0; j < 4; ++j) { hx[j] = (_Float16)sa[p][j]; hx[4 + j] = (_Float16)sb[p][j]; }
      const int ch = (4 + p) * 8 + sseg;
      *(half8*)(xs + srow * D_DIM + ((ch ^ skey) * 8)) = hx;
    }
  }
  __syncthreads();

  // ---- K-loop: A-frags from LDS, B-frags from packed global (L2); no barriers
  f32x4 acc[2][4];
#pragma unroll
  for (int mi = 0; mi < 2; ++mi)
#pragma unroll
    for (int nf = 0; nf < 4; ++nf) acc[mi][nf] = (f32x4){0.f, 0.f, 0.f, 0.f};
#pragma unroll
  for (int tk = 0; tk < 16; ++tk) {
    const int slot = ((tk * 4 + fg) ^ akey) * 8;
    half8 af0 = *(const half8*)(xs + (fr) * D_DIM + slot);
    half8 af1 = *(const half8*)(xs + (16 + fr) * D_DIM + slot);
    half8 bf0 = *(const half8*)(wp + (0 * 16 + tk) * 512);
    half8 bf1 = *(const half8*)(wp + (1 * 16 + tk) * 512);
    half8 bf2 = *(const half8*)(wp + (2 * 16 + tk) * 512);
    half8 bf3 = *(const half8*)(wp + (3 * 16 + tk) * 512);
    acc[0][0] = __builtin_amdgcn_mfma_f32_16x16x32_f16(af0, bf0, acc[0][0], 0, 0, 0);
    acc[0][1] = __builtin_amdgcn_mfma_f32_16x16x32_f16(af0, bf1, acc[0][1], 0, 0, 0);
    acc[0][2] = __builtin_amdgcn_mfma_f32_16x16x32_f16(af0, bf2, acc[0][2], 0, 0, 0);
    acc[0][3] = __builtin_amdgcn_mfma_f32_16x16x32_f16(af0, bf3, acc[0][3], 0, 0, 0);
    acc[1][0] = __builtin_amdgcn_mfma_f32_16x16x32_f16(af1, bf0, acc[1][0], 0, 0, 0);
    acc[1][1] = __builtin_amdgcn_mfma_f32_16x16x32_f16(af1, bf1, acc[1][1], 0, 0, 0);
    acc[1][2] = __builtin_amdgcn_mfma_f32_16x16x32_f16(af1, bf2, acc[1][2], 0, 0, 0);
    acc[1][3] = __builtin_amdgcn_mfma_f32_16x16x32_f16(af1, bf3, acc[1][3], 0, 0, 0);
  }

  // ---- epilogue: score partial for this wave's 64 acols (C frag: row=fg*4+r)
  {
    float part[2][4];
#pragma unroll
    for (int mi = 0; mi < 2; ++mi)
#pragma unroll
      for (int r = 0; r < 4; ++r) part[mi][r] = 0.f;
#pragma unroll
    for (int nf = 0; nf < 4; ++nf)
#pragma unroll
      for (int mi = 0; mi < 2; ++mi)
#pragma unroll
        for (int r = 0; r < 4; ++r)
          part[mi][r] += wt_a[nf] * tanh_fast(acc[mi][nf][r] + whb_a[nf]);
#pragma unroll
    for (int mask = 1; mask < 16; mask <<= 1)
#pragma unroll
      for (int mi = 0; mi < 2; ++mi)
#pragma unroll
        for (int r = 0; r < 4; ++r) part[mi][r] += __shfl_xor(part[mi][r], mask, 64);
    if (fr == 0) {
#pragma unroll
      for (int mi = 0; mi < 2; ++mi)
#pragma unroll
        for (int r = 0; r < 4; ++r)
          scorep[wv * BM + mi * 16 + fg * 4 + r] = part[mi][r];
    }
  }
  __syncthreads();

  // ---- tile-local softmax (32 rows; both 32-lane halves compute identically)
  const int rl = lane & 31;
  float sv = scorep[rl] + scorep[BM + rl] + scorep[2 * BM + rl] + scorep[3 * BM + rl];
  float m = sv;
#pragma unroll
  for (int mask = 1; mask < 32; mask <<= 1) m = fmaxf(m, __shfl_xor(m, mask, 64));
  float p = __expf(sv - m);
  float lsum = p;
#pragma unroll
  for (int mask = 1; mask < 32; mask <<= 1) lsum += __shfl_xor(lsum, mask, 64);
  if (tid == 0) {
    m_arr[b * NTILES + tile] = m;
    l_arr[b * NTILES + tile] = lsum;
  }

  // ---- weighted sum from resident tile: wave owns 16 chunks (128 cols)
  {
    const int q = lane >> 4;                 // 4 row-groups of 8
    const int ch = wv * 16 + (lane & 15);    // chunk 0..63
    float wacc[8];
#pragma unroll
    for (int j = 0; j < 8; ++j) wacc[j] = 0.f;
#pragma unroll
    for (int k = 0; k < 8; ++k) {
      const int row = q * 8 + k;
      const float pr = __shfl(p, row, 64);
      half8 xv = *(const half8*)(xs + row * D_DIM + ((ch ^ (row & 7)) * 8));
#pragma unroll
      for (int j = 0; j < 8; ++j) wacc[j] += pr * (float)xv[j];
    }
#pragma unroll
    for (int j = 0; j < 8; ++j) wacc[j] += __shfl_xor(wacc[j], 16, 64);
#pragma unroll
    for (int j = 0; j < 8; ++j) wacc[j] += __shfl_xor(wacc[j], 32, 64);
    if (lane < 16) {
      float* ob = acc_arr + ((size_t)(b * NTILES + tile)) * D_DIM + ch * 8;
      *(f32x4*)(ob) = (f32x4){wacc[0], wacc[1], wacc[2], wacc[3]};
      *(f32x4*)(ob + 4) = (f32x4){wacc[4], wacc[5], wacc[6], wacc[7]};
    }
  }
}

__global__ void __launch_bounds__(512)
combine_kernel(const float* __restrict__ m_arr, const float* __restrict__ l_arr,
               const float* __restrict__ acc_arr, float* __restrict__ out) {
  __shared__ float ml[NTILES], ls[NTILES], wl[NTILES];
  const int b = blockIdx.x, tid = threadIdx.x;
  if (tid < NTILES) {
    ml[tid] = m_arr[b * NTILES + tid];
    ls[tid] = l_arr[b * NTILES + tid];
  }
  __syncthreads();
  float M = -1e30f;
  for (int i = 0; i < NTILES; ++i) M = fmaxf(M, ml[i]);
  if (tid < NTILES) wl[tid] = __expf(ml[tid] - M);
  __syncthreads();
  float L = 0.f;
  for (int i = 0; i < NTILES; ++i) L += wl[i] * ls[i];
  float sum = 0.f;
  const size_t base = (size_t)b * NTILES * D_DIM + tid;
  for (int i = 0; i < NTILES; ++i) sum += wl[i] * acc_arr[base + (size_t)i * D_DIM];
  out[b * D_DIM + tid] = sum / L;
}

extern "C" void kernel_launch(void* const* d_in, const int* in_sizes, int n_in,
                              void* d_out, int out_size, void* d_ws, size_t ws_size,
                              hipStream_t stream) {
  const float* x = (const float*)d_in[0];
  const float* h = (const float*)d_in[1];
  const float* Wx = (const float*)d_in[2];
  const float* bx = (const float*)d_in[3];
  const float* Wh = (const float*)d_in[4];
  const float* Wt = (const float*)d_in[5];
  // d_in[6] = bt: unused (softmax shift-invariant)

  char* ws = (char*)d_ws;
  _Float16* Wp = (_Float16*)ws;                               // 262144 B (packed)
  float* whb = (float*)(ws + 262144);                         // 65536 B
  float* m_arr = (float*)(ws + 262144 + 65536);               // 65536 B
  float* l_arr = (float*)(ws + 262144 + 65536 + 65536);       // 65536 B
  float* acc_arr = (float*)(ws + 262144 + 3 * 65536);         // 33.6 MB

  hipLaunchKernelGGL(convw_kernel, dim3(64), dim3(256), 0, stream, Wx, Wp);
  hipLaunchKernelGGL(whb_kernel, dim3(B_DIM), dim3(256), 0, stream, h, Wh, bx, whb);
  hipLaunchKernelGGL(paa_main, dim3(B_DIM, NTILES), dim3(256), 0, stream,
                     x, Wp, whb, Wt, m_arr, l_arr, acc_arr);
  hipLaunchKernelGGL(combine_kernel, dim3(B_DIM), dim3(512), 0, stream,
                     m_arr, l_arr, acc_arr, (float*)d_out);
}